// Round 7
// baseline (644.961 us; speedup 1.0000x reference)
//
#include <hip/hip_runtime.h>
#include <hip/hip_fp16.h>

// SpikingLinear on MI355X:
//   lin = input[:-1] @ W^T   (M=32512, N=1024, K=1024)  via split-fp16 MFMA:
//     A = Ah + Al, W = Wh + Wl  (fp16 RTN hi + fp16 residual lo)
//     lin ~= Ah*Wh + Ah*Wl + Al*Wh   (3 passes, fp32 acc)
//   GEMM v6: R6's fused-split 6-phase skeleton, MFMA core switched to
//   mfma_f32_32x32x16_f16 (+11% rate vs 16x16x32: 2178 vs 1955 TF ubench;
//   half the MFMA instruction count -> issue-slot relief at 2 waves/SIMD).
//   Wave tile 128x64 = 4x2 frags of 32x32, acc = 8 x f32x16 = 128 VGPR.
//   LDS image/staging/swizzle identical to R6; only read addressing,
//   MFMA calls (8/phase) and C-store layout (m74/m101-verified) change.
//   8 waves = 2M x 4N.  1 block/CU (128KB LDS).
//   Scan vectorized to float2 (BW-bound, G13).
//
// Buffer reuse (no d_ws): Wh/Wl (4MB) in the V-output plane.  GEMM writes lin
// into the I-output plane at step t+1.  Scan overwrites everything afterwards.
// All kernels serialized on `stream`.

#define STEPS 128
#define BATCH 256
#define DIN   1024
#define DOUT  1024

#define ALPHA 0.7788007830714049f   // exp(-1/4)
#define BETA  0.9512294245007140f   // exp(-1/20)

constexpr int    GM      = (STEPS - 1) * BATCH;        // 32512 GEMM rows
constexpr size_t PLANE   = (size_t)BATCH * DOUT;       // 262144 elems / step
constexpr size_t W_ELEMS = (size_t)DOUT * DIN;         // 1,048,576

typedef __attribute__((ext_vector_type(8)))  _Float16 half8;   // 8 fp16 = 4 VGPR
typedef __attribute__((ext_vector_type(16))) float    f32x16;  // 32x32 C/D
typedef __attribute__((ext_vector_type(2)))  float    f32x2;

// ---------------------------------------------------------------- split ----
// (W only -- 4 MB, ~2 us)
__global__ __launch_bounds__(256)
void split_kernel(const float* __restrict__ x,
                  unsigned short* __restrict__ hi,
                  unsigned short* __restrict__ lo)
{
    const size_t i = (size_t)blockIdx.x * 256 + threadIdx.x;   // float4 index
    const float4 v = reinterpret_cast<const float4*>(x)[i];
    float f[4] = {v.x, v.y, v.z, v.w};
    unsigned short hb[4], lb[4];
#pragma unroll
    for (int j = 0; j < 4; ++j) {
        _Float16 h = (_Float16)f[j];                       // RTN
        _Float16 l = (_Float16)(f[j] - (float)h);          // exact residual, RTN
        hb[j] = *reinterpret_cast<unsigned short*>(&h);
        lb[j] = *reinterpret_cast<unsigned short*>(&l);
    }
    ushort4 hv = {hb[0], hb[1], hb[2], hb[3]};
    ushort4 lv = {lb[0], lb[1], lb[2], lb[3]};
    reinterpret_cast<ushort4*>(hi)[i] = hv;
    reinterpret_cast<ushort4*>(lo)[i] = lv;
}

// ----------------------------------------------------------------- gemm ----
__device__ __forceinline__ void load16(const unsigned short* g, unsigned short* l)
{
    __builtin_amdgcn_global_load_lds(
        (const __attribute__((address_space(1))) void*)g,
        (__attribute__((address_space(3))) void*)l, 16, 0, 0);
}

__device__ __forceinline__ half8 ldsr(unsigned addr)
{
    half8 r;
    asm volatile("ds_read_b128 %0, %1" : "=v"(r) : "v"(addr) : "memory");
    return r;
}

#define PHASE_PRE() do {                                        \
    __builtin_amdgcn_s_barrier();                               \
    asm volatile("s_waitcnt lgkmcnt(0)" ::: "memory");          \
    __builtin_amdgcn_sched_barrier(0);                          \
    __builtin_amdgcn_s_setprio(1);                              \
} while (0)

#define PHASE_POST() do {                                       \
    __builtin_amdgcn_s_setprio(0);                              \
    __builtin_amdgcn_sched_barrier(0);                          \
    __builtin_amdgcn_s_barrier();                               \
} while (0)

// 8 MFMA: 4 m-frags x 2 n-frags of 32x32x16
#define MFMA8(AARR, AO, BARR, BO)                               \
    _Pragma("unroll")                                           \
    for (int fm = 0; fm < 4; ++fm)                              \
        _Pragma("unroll")                                       \
        for (int fn = 0; fn < 2; ++fn)                          \
            acc[fm][fn] = __builtin_amdgcn_mfma_f32_32x32x16_f16( \
                AARR[(AO) + fm], BARR[(BO) + fn], acc[fm][fn], 0, 0, 0)

__global__ __launch_bounds__(512, 2)
void gemm_kernel(const float* __restrict__ Af,
                 const unsigned short* __restrict__ Wh,
                 const unsigned short* __restrict__ Wl,
                 float* __restrict__ C)
{
    // 2 slots of 64 KiB: {Ah 16KB | Al 16KB | Bh 16KB | Bl 16KB},
    // each array 256 rows x 32 k fp16 (row = 64 B).
    __shared__ __align__(16) unsigned short smem[65536];   // 128 KiB

    // XCD-chunked 1D grid (512 blocks)
    const int lin = blockIdx.x;
    const int xcd = lin & 7, slot = lin >> 3;          // slot 0..63
    const int mp  = xcd * 16 + (slot >> 2);            // m-panel
    const int nt  = slot & 3;
    if (mp >= GM / 256) return;                        // 127 real panels
    const int m0 = mp * 256;
    const int n0 = nt * 256;

    const int t = threadIdx.x;
    const int w = t >> 6, l = t & 63;
    const int wr = w >> 2, wc = w & 3;                 // 2M x 4N waves

    // swizzle (LDS image identical to R6): LDS[r][g] = global[r][g ^ ((r>>1)&3)]
    // 32x32 fragment: lane holds row (l&31), k = (l>>5)*8 + j (+16 for ks1).
    const unsigned xorb = (unsigned)(((l >> 1) & 3) * 16);
    const unsigned g0b  = ((unsigned)((l >> 5) * 16)) ^ xorb;        // ks0 granule byte
    const unsigned g1b  = ((unsigned)((2 + (l >> 5)) * 16)) ^ xorb;  // ks1 granule byte

    const unsigned rdA  = (unsigned)((wr * 128 + (l & 31)) * 64);          // A-hi; +16384 = A-lo
    const unsigned rdB  = (unsigned)(32768 + (wc * 64 + (l & 31)) * 64);   // B-hi; +16384 = B-lo

    // staging geometry (identical to R6):
    const int srow = l >> 2;
    const int sgE  = ((l & 3) ^ ((l >> 3) & 3)) * 8;   // element offset

    const size_t fA0 = (size_t)(m0 + w * 32 +      srow) * DIN + sgE;  // A f32
    const size_t fA1 = (size_t)(m0 + w * 32 + 16 + srow) * DIN + sgE;
    const size_t sB0 = (size_t)(n0 + w * 32 +      srow) * DIN + sgE;  // W fp16
    const size_t sB1 = (size_t)(n0 + w * 32 + 16 + srow) * DIN + sgE;

    const unsigned dstA = (unsigned)(w * 1024 + l * 8);   // ushort idx in slot

    auto STAGE_W = [&](int ks) {
        const int kk = (ks & 31) << 5;
        unsigned short* d = smem + ((ks & 1) << 15) + w * 1024;
        load16(Wh + sB0 + kk, d + 16384);
        load16(Wh + sB1 + kk, d + 16896);
        load16(Wl + sB0 + kk, d + 24576);
        load16(Wl + sB1 + kk, d + 25088);
    };

    auto WRITE_A = [&](float4 x, float4 y, unsigned short* ds, unsigned off) {
        float f[8] = {x.x, x.y, x.z, x.w, y.x, y.y, y.z, y.w};
        half8 h, lo8;
#pragma unroll
        for (int j = 0; j < 8; ++j) {
            _Float16 hh = (_Float16)f[j];              // RTN
            h[j]   = hh;
            lo8[j] = (_Float16)(f[j] - (float)hh);     // exact residual, RTN
        }
        *reinterpret_cast<half8*>(ds + dstA + off)        = h;
        *reinterpret_cast<half8*>(ds + dstA + off + 8192) = lo8;
    };

    f32x16 acc[4][2];
#pragma unroll
    for (int fm = 0; fm < 4; ++fm)
#pragma unroll
        for (int fn = 0; fn < 2; ++fn)
#pragma unroll
            for (int rg = 0; rg < 16; ++rg)
                acc[fm][fn][rg] = 0.f;

    // ---- prologue: build slot 0 (tile 0), full drain (one-time) ----------
    {
        float4 a0 = *reinterpret_cast<const float4*>(Af + fA0);
        float4 a1 = *reinterpret_cast<const float4*>(Af + fA0 + 4);
        float4 a2 = *reinterpret_cast<const float4*>(Af + fA1);
        float4 a3 = *reinterpret_cast<const float4*>(Af + fA1 + 4);
        STAGE_W(0);
        unsigned short* ds = smem;                      // slot 0
        WRITE_A(a0, a1, ds, 0);
        WRITE_A(a2, a3, ds, 512);
        asm volatile("s_waitcnt vmcnt(0) lgkmcnt(0)" ::: "memory");
        __builtin_amdgcn_s_barrier();
    }

    for (int kt = 0; kt < 32; ++kt) {
        const unsigned sb = (unsigned)((kt & 1) << 16);   // slot byte base
        const int kn = ((kt + 1) & 31) << 5;              // next tile k0
        half8 ahi[8], alo[8], bhi[4], blo[4];

        // ---- P0: issue A(t+1) f32 loads; ahi(ks0) + bhi(ks0,ks1); hh-ks0 -
        float4 a0 = *reinterpret_cast<const float4*>(Af + fA0 + kn);
        float4 a1 = *reinterpret_cast<const float4*>(Af + fA0 + kn + 4);
        float4 a2 = *reinterpret_cast<const float4*>(Af + fA1 + kn);
        float4 a3 = *reinterpret_cast<const float4*>(Af + fA1 + kn + 4);
#pragma unroll
        for (int fm = 0; fm < 4; ++fm) ahi[fm] = ldsr(sb + rdA + fm * 2048 + g0b);
#pragma unroll
        for (int fn = 0; fn < 2; ++fn) {
            bhi[fn]     = ldsr(sb + rdB + fn * 2048 + g0b);
            bhi[2 + fn] = ldsr(sb + rdB + fn * 2048 + g1b);
        }
        PHASE_PRE();  MFMA8(ahi, 0, bhi, 0);  PHASE_POST();

        // ---- P1: ahi(ks1); hh-ks1 ----------------------------------------
#pragma unroll
        for (int fm = 0; fm < 4; ++fm) ahi[4 + fm] = ldsr(sb + rdA + fm * 2048 + g1b);
        PHASE_PRE();  MFMA8(ahi, 4, bhi, 2);  PHASE_POST();

        // ---- P2: blo(ks0,ks1); stage W(t+1); hl-ks0 ----------------------
#pragma unroll
        for (int fn = 0; fn < 2; ++fn) {
            blo[fn]     = ldsr(sb + rdB + 16384 + fn * 2048 + g0b);
            blo[2 + fn] = ldsr(sb + rdB + 16384 + fn * 2048 + g1b);
        }
        STAGE_W((kt + 1) & 31);
        PHASE_PRE();  MFMA8(ahi, 0, blo, 0);  PHASE_POST();

        // ---- P3: alo(ks0); hl-ks1 ----------------------------------------
#pragma unroll
        for (int fm = 0; fm < 4; ++fm) alo[fm] = ldsr(sb + rdA + 16384 + fm * 2048 + g0b);
        PHASE_PRE();  MFMA8(ahi, 4, blo, 2);  PHASE_POST();

        // ---- P4: alo(ks1); lh-ks0 ----------------------------------------
#pragma unroll
        for (int fm = 0; fm < 4; ++fm) alo[4 + fm] = ldsr(sb + rdA + 16384 + fm * 2048 + g1b);
        PHASE_PRE();  MFMA8(alo, 0, bhi, 0);  PHASE_POST();

        // ---- P5: lh-ks1; cvt+ds_write A(t+1); tile drain -----------------
        PHASE_PRE();  MFMA8(alo, 4, bhi, 2);
        __builtin_amdgcn_s_setprio(0);
        __builtin_amdgcn_sched_barrier(0);
        {
            unsigned short* ds = smem + (((kt + 1) & 1) << 15);
            WRITE_A(a0, a1, ds, 0);        // compiler auto-waits vmcnt here
            WRITE_A(a2, a3, ds, 512);
        }
        // W(t+1) issued 3 phases ago -> drain already met; lgkm drains our
        // ds_writes; barrier makes slot t+1 cross-wave-valid.
        asm volatile("s_waitcnt vmcnt(0) lgkmcnt(0)" ::: "memory");
        __builtin_amdgcn_s_barrier();
    }

    // 32x32 C/D layout: col = lane&31, row = (reg&3) + 8*(reg>>2) + 4*(lane>>5)
    // [m74/m101 verified]
    const int mwb = m0 + wr * 128 + ((l >> 5) << 2);
    const int nwb = n0 + wc * 64 + (l & 31);
#pragma unroll
    for (int fm = 0; fm < 4; ++fm)
#pragma unroll
        for (int fn = 0; fn < 2; ++fn)
#pragma unroll
            for (int rg = 0; rg < 16; ++rg)
                C[(size_t)(mwb + fm * 32 + (rg & 3) + ((rg >> 2) << 3)) * DOUT
                  + nwb + fn * 32] = acc[fm][fn][rg];
}

// ----------------------------------------------------------------- scan ----
__global__ __launch_bounds__(256)
void scan_kernel(float* __restrict__ out)
{
    const int idx = blockIdx.x * 256 + threadIdx.x;           // f32x2 index
    constexpr int P2 = (int)(PLANE / 2);
    f32x2* o0 = reinterpret_cast<f32x2*>(out);                 // spk
    f32x2* o1 = reinterpret_cast<f32x2*>(out + STEPS * PLANE); // V
    f32x2* o2 = reinterpret_cast<f32x2*>(out + 2 * STEPS * PLANE); // I / lin

    const f32x2 z = {0.f, 0.f};
    __builtin_nontemporal_store(z, &o0[idx]);
    __builtin_nontemporal_store(z, &o1[idx]);
    __builtin_nontemporal_store(z, &o2[idx]);

    // depth-3 prefetch of lin reads
    f32x2 n1 = o2[idx + P2];
    f32x2 n2 = o2[idx + 2 * P2];
    f32x2 n3 = o2[idx + 3 * P2];

    f32x2 syn = z, mem = z;
    size_t off = idx;
    for (int i = 1; i < STEPS; ++i) {
        off += P2;
        const f32x2 cur = n1; n1 = n2; n2 = n3;
        if (i + 3 < STEPS) n3 = o2[off + 3 * P2];
        f32x2 reset;
        reset.x = (mem.x > 1.0f) ? 1.0f : 0.0f;
        reset.y = (mem.y > 1.0f) ? 1.0f : 0.0f;
        syn = ALPHA * syn + cur;
        mem = (BETA * mem + syn) * (1.0f - reset);
        f32x2 spk;
        spk.x = (mem.x > 1.0f) ? 1.0f : 0.0f;
        spk.y = (mem.y > 1.0f) ? 1.0f : 0.0f;
        __builtin_nontemporal_store(spk, &o0[off]);
        __builtin_nontemporal_store(mem, &o1[off]);
        __builtin_nontemporal_store(syn, &o2[off]);
    }
}

// --------------------------------------------------------------- launch ----
extern "C" void kernel_launch(void* const* d_in, const int* in_sizes, int n_in,
                              void* d_out, int out_size, void* d_ws, size_t ws_size,
                              hipStream_t stream)
{
    const float* input  = (const float*)d_in[0];   // [128, 256, 1024]
    const float* weight = (const float*)d_in[1];   // [1024, 1024]
    float* out = (float*)d_out;

    unsigned short* Wh = (unsigned short*)(out + STEPS * PLANE);   // V plane
    unsigned short* Wl = Wh + W_ELEMS;
    float* lin = out + 2 * STEPS * PLANE + PLANE;                  // I plane, t>=1

    split_kernel<<<(int)(W_ELEMS / 1024), 256, 0, stream>>>(weight, Wh, Wl);

    gemm_kernel<<<512, 512, 0, stream>>>(input, Wh, Wl, lin);

    scan_kernel<<<(int)(PLANE / 512), 256, 0, stream>>>(out);
}